// Round 9
// baseline (246.442 us; speedup 1.0000x reference)
//
#include <hip/hip_runtime.h>

// MultiHeadSelfAttention: B=2 T=2048 C=1024 H=16 D=64, causal, f32 in/out.
// R8: (a) attn v2: S^T orientation (swap MFMA operands) -> in-lane bf16 P
// packing, small Pl (4.6KB/wave), single-buffer Vt -> 18.4KB LDS/block,
// 4-way j-split (2048 blocks, 16 waves/CU), atomic partial (o,l) accumulation
// + finalize. (b) permuted in_w -> GEMM writes qkv layout directly (repack
// kernel deleted); K pre-scaled by D^-0.5*log2e in GEMM epilogue.
// einops factoring: col c of (3C) = d*48 + s*16 + h, with s: 0=Q, 1=V, 2=K.

#define BB 2
#define TT 2048
#define CC 1024
#define HH 16
#define DD 64
#define MM (BB*TT)   // 4096
#define N3 (3*CC)    // 3072
#define BH (BB*HH)   // 32
#define KSCALE 0.18033688011112042f  // 1/8 * log2(e)

typedef unsigned short u16;
typedef unsigned int   u32;
typedef __bf16 bf16x8 __attribute__((ext_vector_type(8)));
typedef float  f32x4  __attribute__((ext_vector_type(4)));

__device__ __forceinline__ u16 f32_to_bf16(float f) {
  u32 u = __float_as_uint(f);
  return (u16)((u + 0x7fffu + ((u >> 16) & 1u)) >> 16);  // RNE
}
__device__ __forceinline__ u32 pack2_bf16(float a, float b) {
  u32 ua = __float_as_uint(a) + 0x8000u;
  u32 ub = __float_as_uint(b) + 0x8000u;
  return __builtin_amdgcn_perm(ub, ua, 0x07060302);  // bf16(a) | bf16(b)<<16
}

// ---------------- fused cast f32 -> bf16; in_w rows PERMUTED ----------------
// wb row r' = s*1024 + h*64 + d  <-  in_w row d*48 + s*16 + h
#define N4_X  (MM * CC / 4)          // 1048576
#define N4_W  (N3 * CC / 4)          //  786432
#define N4_OW (CC * CC / 4)          //  262144
__global__ __launch_bounds__(256) void cast_all(const float* __restrict__ x,
                                                const float* __restrict__ in_w,
                                                const float* __restrict__ out_w,
                                                u16* __restrict__ xb,
                                                u16* __restrict__ wb,
                                                u16* __restrict__ owb) {
  int i = blockIdx.x * 256 + threadIdx.x;
  const float* src; u16* dst; int j; int sj;
  if (i < N4_X)             { src = x;     dst = xb;  j = i;               sj = j; }
  else if (i < N4_X + N4_W) { src = in_w;  dst = wb;  j = i - N4_X;
                              int rp = j >> 8, c = j & 255;
                              int s = rp >> 10, h = (rp >> 6) & 15, d = rp & 63;
                              sj = (d * 48 + s * 16 + h) * 256 + c; }
  else                      { src = out_w; dst = owb; j = i - N4_X - N4_W; sj = j; }
  float4 f = reinterpret_cast<const float4*>(src)[sj];
  uint2 pk;
  pk.x = (u32)f32_to_bf16(f.x) | ((u32)f32_to_bf16(f.y) << 16);
  pk.y = (u32)f32_to_bf16(f.z) | ((u32)f32_to_bf16(f.w) << 16);
  reinterpret_cast<uint2*>(dst)[j] = pk;
}

// ---------------- tiled GEMM core: 128x128 tile, BK=64, 4 waves (verified R2) ----------------
__device__ __forceinline__ void gemm_core(const u16* __restrict__ Ag,
                                          const u16* __restrict__ Bg,
                                          int K, u16* Al, u16* Bl,
                                          int m0, int n0, f32x4 acc[4][4]) {
  const int tid = threadIdx.x, lane = tid & 63, w = tid >> 6;
  const int quad = lane >> 4, colr = lane & 15;
  const int mw = (w >> 1) * 64, nw = (w & 1) * 64;
  const int srow = lane >> 3, scol = lane & 7;
  const uint4* Al4 = reinterpret_cast<const uint4*>(Al);
  const uint4* Bl4 = reinterpret_cast<const uint4*>(Bl);
  for (int kt = 0; kt < K / 64; ++kt) {
    __syncthreads();
    #pragma unroll
    for (int ii = 0; ii < 4; ++ii) {
      int inst = w * 4 + ii;
      int row = inst * 8 + srow;
      int cs = scol ^ (row & 7);
      const u16* ga = Ag + (size_t)(m0 + row) * K + kt * 64 + cs * 8;
      const u16* gb = Bg + (size_t)(n0 + row) * K + kt * 64 + cs * 8;
      __builtin_amdgcn_global_load_lds(
          (const __attribute__((address_space(1))) void*)ga,
          (__attribute__((address_space(3))) void*)(Al + inst * 512), 16, 0, 0);
      __builtin_amdgcn_global_load_lds(
          (const __attribute__((address_space(1))) void*)gb,
          (__attribute__((address_space(3))) void*)(Bl + inst * 512), 16, 0, 0);
    }
    __syncthreads();
    #pragma unroll
    for (int ks = 0; ks < 2; ++ks) {
      bf16x8 af[4], bfr[4];
      #pragma unroll
      for (int t = 0; t < 4; ++t) {
        int mrow = mw + t * 16 + colr;
        af[t]  = __builtin_bit_cast(bf16x8, Al4[mrow * 8 + ((ks * 4 + quad) ^ (mrow & 7))]);
        int nrow = nw + t * 16 + colr;
        bfr[t] = __builtin_bit_cast(bf16x8, Bl4[nrow * 8 + ((ks * 4 + quad) ^ (nrow & 7))]);
      }
      #pragma unroll
      for (int mt = 0; mt < 4; ++mt)
        #pragma unroll
        for (int nt = 0; nt < 4; ++nt)
          acc[mt][nt] = __builtin_amdgcn_mfma_f32_16x16x32_bf16(af[mt], bfr[nt], acc[mt][nt], 0, 0, 0);
    }
  }
}

// ---------------- QKV GEMM: writes qkv [s][bh][t][d] directly ----------------
// B-operand is permuted wb (cols already [s][h][d]); each (s,h) 64-d group x
// 128 t-rows is block-complete -> coalesced-enough full-line writes. K (s==2)
// scaled by KSCALE here (folds D^-0.5*log2e into scores).
__global__ __launch_bounds__(256) void gemm_qkv(const u16* __restrict__ xb,
                                                const u16* __restrict__ wb,
                                                const float* __restrict__ in_b,
                                                u16* __restrict__ qkv) {
  __shared__ __align__(16) u16 Al[128 * 64];
  __shared__ __align__(16) u16 Bl[128 * 64];
  const int lane = threadIdx.x & 63, w = threadIdx.x >> 6;
  const int quad = lane >> 4, colr = lane & 15;
  const int mw = (w >> 1) * 64, nw = (w & 1) * 64;
  const int m0 = blockIdx.x * 128, n0 = blockIdx.y * 128;
  f32x4 acc[4][4];
  #pragma unroll
  for (int mt = 0; mt < 4; ++mt)
    #pragma unroll
    for (int nt = 0; nt < 4; ++nt) acc[mt][nt] = (f32x4){0.f, 0.f, 0.f, 0.f};
  gemm_core(xb, wb, CC, Al, Bl, m0, n0, acc);
  const int b_ = m0 >> 11;
  #pragma unroll
  for (int nt = 0; nt < 4; ++nt) {
    int np = n0 + nw + nt * 16 + colr;        // permuted col = s*1024+h*64+d
    int s = np >> 10, h = (np >> 6) & 15, d = np & 63;
    float bias = in_b[d * 48 + s * 16 + h];
    float sc = (s == 2) ? KSCALE : 1.0f;
    u16* base = qkv + ((size_t)(s * BH + b_ * HH + h) * TT) * DD + d;
    #pragma unroll
    for (int mt = 0; mt < 4; ++mt)
      #pragma unroll
      for (int e = 0; e < 4; ++e) {
        int t = (m0 + mw + mt * 16 + quad * 4 + e) & (TT - 1);
        base[(size_t)t * DD] = f32_to_bf16((acc[mt][nt][e] + bias) * sc);
      }
  }
}

// ---------------- MFMA flash attention v2 (S^T, split-4, atomic partials) ----------------
// 2048 blocks x 128 thr (2 waves x 32-row strips). f: xcd=f&7, qq=(f>>3)&3,
// pr=(f>>5)&15, bh=xcd*4+(f>>9). Pair (pr,31-pr) virtual j-seq (33 tiles)
// chunked 9/8/8/8 by qq; a chunk is 1-2 (qt, j-range) segments. All partials
// atomicAdd into po[bh*32+qt] (64x64 f32) / pl (64 f32); finalize normalizes.
// K pre-scaled -> exp2 direct. Single-buffer Vt; P^T bf16 in Pl (S^T C-layout
// packs in-lane: j = t4*16+quad*4+rg, q = u*16+colr).
__global__ __launch_bounds__(128, 4) void attn_mfma(const u16* __restrict__ qkv,
                                                    float* __restrict__ po,
                                                    float* __restrict__ pl) {
  __shared__ __align__(16) u32 Vt[64 * 36];      // V^T bf16-pairs (single buf)
  __shared__ __align__(16) u32 Pl[2 * 32 * 36];  // per-wave P^T bf16, row=q(32), 36 words
  const int tid  = threadIdx.x;
  const int lane = tid & 63, w = tid >> 6;       // w in 0..1
  const int quad = lane >> 4, colr = lane & 15;
  const int f = blockIdx.x;
  const int qq = (f >> 3) & 3;
  const int pr = (f >> 5) & 15;
  const int bh = (f & 7) * 4 + (f >> 9);

  const uint4* Qg4 = reinterpret_cast<const uint4*>(qkv + (size_t)bh * TT * DD);
  const uint4* Vg4 = reinterpret_cast<const uint4*>(qkv + ((size_t)BH + bh) * TT * DD);
  const uint4* Kg4 = reinterpret_cast<const uint4*>(qkv + ((size_t)2 * BH + bh) * TT * DD);
  const uint4* Vt4 = reinterpret_cast<const uint4*>(Vt);
  const uint4* Pl4 = reinterpret_cast<const uint4*>(Pl);

  const int s_jp = tid & 31, s_half = tid >> 5;  // V staging map
  const int wb32 = w * (32 * 36);                // Pl word base per wave

  // chunk -> up to 2 segments
  const int vlo = (qq == 0) ? 0 : (qq * 8 + 1);
  const int vhi = qq * 8 + 8;
  int sqt[2], sjlo[2], sjhi[2], nseg = 0;
  if (vlo <= pr) { sqt[nseg] = pr; sjlo[nseg] = vlo; sjhi[nseg] = vhi < pr ? vhi : pr; ++nseg; }
  if (vhi > pr)  { sqt[nseg] = 31 - pr;
                   int lo = (vlo > pr + 1 ? vlo : pr + 1) - (pr + 1);
                   sjlo[nseg] = lo; sjhi[nseg] = vhi - (pr + 1); ++nseg; }

  for (int sg = 0; sg < nseg; ++sg) {
    const int qt = sqt[sg], jlo = sjlo[sg], jhi = sjhi[sg];
    const int i0 = qt * 64;

    bf16x8 qa[2][2];
    #pragma unroll
    for (int u = 0; u < 2; ++u)
      #pragma unroll
      for (int ks = 0; ks < 2; ++ks)
        qa[u][ks] = __builtin_bit_cast(bf16x8,
            Qg4[(size_t)(i0 + w * 32 + u * 16 + colr) * 8 + ks * 4 + quad]);

    f32x4 oacc[2][4];
    #pragma unroll
    for (int u = 0; u < 2; ++u)
      #pragma unroll
      for (int dt = 0; dt < 4; ++dt) oacc[u][dt] = (f32x4){0.f, 0.f, 0.f, 0.f};
    float lp[2] = {0.f, 0.f};

    uint4 va[2], vb[2];
    #pragma unroll
    for (int io = 0; io < 2; ++io) {
      va[io] = Vg4[(size_t)(jlo * 64 + 2 * s_jp) * 8 + s_half + io * 4];
      vb[io] = Vg4[(size_t)(jlo * 64 + 2 * s_jp + 1) * 8 + s_half + io * 4];
    }

    for (int jt = jlo; jt <= jhi; ++jt) {
      const int j0 = jt * 64;
      __syncthreads();  // previous tile's / segment's Vt readers done
      #pragma unroll
      for (int io = 0; io < 2; ++io) {
        const int oc = s_half + io * 4;
        u32 aw[4] = {va[io].x, va[io].y, va[io].z, va[io].w};
        u32 bw[4] = {vb[io].x, vb[io].y, vb[io].z, vb[io].w};
        #pragma unroll
        for (int m = 0; m < 4; ++m) {
          Vt[(oc * 8 + 2 * m)     * 36 + s_jp] = __builtin_amdgcn_perm(bw[m], aw[m], 0x05040100);
          Vt[(oc * 8 + 2 * m + 1) * 36 + s_jp] = __builtin_amdgcn_perm(bw[m], aw[m], 0x07060302);
        }
      }
      if (jt < jhi) {
        int nj = j0 + 64;
        #pragma unroll
        for (int io = 0; io < 2; ++io) {
          va[io] = Vg4[(size_t)(nj + 2 * s_jp) * 8 + s_half + io * 4];
          vb[io] = Vg4[(size_t)(nj + 2 * s_jp + 1) * 8 + s_half + io * 4];
        }
      }
      __syncthreads();  // Vt ready

      // ---- S^T = K·Q^T (row=j-local, col=q-local), ks-split K loads ----
      f32x4 sacc[2][4];
      #pragma unroll
      for (int u = 0; u < 2; ++u)
        #pragma unroll
        for (int t4 = 0; t4 < 4; ++t4) sacc[u][t4] = (f32x4){0.f, 0.f, 0.f, 0.f};
      #pragma unroll
      for (int ks = 0; ks < 2; ++ks) {
        uint4 kk[4];
        #pragma unroll
        for (int t4 = 0; t4 < 4; ++t4)
          kk[t4] = Kg4[(size_t)(j0 + t4 * 16 + colr) * 8 + ks * 4 + quad];
        #pragma unroll
        for (int t4 = 0; t4 < 4; ++t4) {
          bf16x8 kb = __builtin_bit_cast(bf16x8, kk[t4]);
          #pragma unroll
          for (int u = 0; u < 2; ++u)
            sacc[u][t4] = __builtin_amdgcn_mfma_f32_16x16x32_bf16(kb, qa[u][ks], sacc[u][t4], 0, 0, 0);
        }
      }

      // ---- exp2 + (diag) mask -> pack bf16 in-lane -> Pl ----
      if (jt == qt) {
        #pragma unroll
        for (int u = 0; u < 2; ++u) {
          const int qv = w * 32 + u * 16 + colr;
          #pragma unroll
          for (int t4 = 0; t4 < 4; ++t4) {
            float p0 = __builtin_amdgcn_exp2f(sacc[u][t4][0]);
            float p1 = __builtin_amdgcn_exp2f(sacc[u][t4][1]);
            float p2 = __builtin_amdgcn_exp2f(sacc[u][t4][2]);
            float p3 = __builtin_amdgcn_exp2f(sacc[u][t4][3]);
            int jb = t4 * 16 + quad * 4;
            if (jb + 0 > qv) p0 = 0.f;
            if (jb + 1 > qv) p1 = 0.f;
            if (jb + 2 > qv) p2 = 0.f;
            if (jb + 3 > qv) p3 = 0.f;
            lp[u] += (p0 + p1) + (p2 + p3);
            uint2 pw; pw.x = pack2_bf16(p0, p1); pw.y = pack2_bf16(p2, p3);
            *reinterpret_cast<uint2*>(Pl + wb32 + (u * 16 + colr) * 36 + t4 * 8 + quad * 2) = pw;
          }
        }
      } else {
        #pragma unroll
        for (int u = 0; u < 2; ++u)
          #pragma unroll
          for (int t4 = 0; t4 < 4; ++t4) {
            float p0 = __builtin_amdgcn_exp2f(sacc[u][t4][0]);
            float p1 = __builtin_amdgcn_exp2f(sacc[u][t4][1]);
            float p2 = __builtin_amdgcn_exp2f(sacc[u][t4][2]);
            float p3 = __builtin_amdgcn_exp2f(sacc[u][t4][3]);
            lp[u] += (p0 + p1) + (p2 + p3);
            uint2 pw; pw.x = pack2_bf16(p0, p1); pw.y = pack2_bf16(p2, p3);
            *reinterpret_cast<uint2*>(Pl + wb32 + (u * 16 + colr) * 36 + t4 * 8 + quad * 2) = pw;
          }
      }

      // ---- PV: A = P (from Pl, b128), B = V^T frags ----
      #pragma unroll
      for (int u = 0; u < 2; ++u) {
        bf16x8 pa[2];
        #pragma unroll
        for (int ks = 0; ks < 2; ++ks)
          pa[ks] = __builtin_bit_cast(bf16x8,
              Pl4[(wb32 + (u * 16 + colr) * 36 + ks * 16 + quad * 4) >> 2]);
        #pragma unroll
        for (int dt = 0; dt < 4; ++dt)
          #pragma unroll
          for (int ks = 0; ks < 2; ++ks) {
            bf16x8 vfr = __builtin_bit_cast(bf16x8, Vt4[(dt * 16 + colr) * 9 + ks * 4 + quad]);
            oacc[u][dt] = __builtin_amdgcn_mfma_f32_16x16x32_bf16(pa[ks], vfr, oacc[u][dt], 0, 0, 0);
          }
      }
    }

    // ---- emit partials (atomic) ----
    const int slot = bh * 32 + qt;
    float* ob = po + (size_t)slot * 4096;
    #pragma unroll
    for (int u = 0; u < 2; ++u) {
      float ls = lp[u];
      ls += __shfl_xor(ls, 16);
      ls += __shfl_xor(ls, 32);   // row-sum for q = u*16+colr, replicated
      if (quad == 0) atomicAdd(&pl[slot * 64 + w * 32 + u * 16 + colr], ls);
      #pragma unroll
      for (int dt = 0; dt < 4; ++dt)
        #pragma unroll
        for (int rg = 0; rg < 4; ++rg)
          atomicAdd(&ob[(w * 32 + u * 16 + quad * 4 + rg) * 64 + dt * 16 + colr],
                    oacc[u][dt][rg]);
    }
  }
}

// ---------------- finalize: ab = po / pl (bf16) ----------------
__global__ __launch_bounds__(256) void attn_finalize(const float* __restrict__ po,
                                                     const float* __restrict__ pl,
                                                     u16* __restrict__ ab) {
  const int slot = blockIdx.x;           // bh*32 + qt
  const int bh = slot >> 5, qt = slot & 31;
  const int b_ = bh >> 4, h = bh & 15;
  const int t = threadIdx.x;
  const int r = t >> 2, dq = t & 3;
  const float4* o4 = reinterpret_cast<const float4*>(po + (size_t)slot * 4096 + r * 64 + dq * 16);
  float inv = 1.0f / pl[slot * 64 + r];
  u16* dst = ab + ((size_t)(b_ * TT + qt * 64 + r)) * CC + h * DD + dq * 16;
  #pragma unroll
  for (int c = 0; c < 4; ++c) {
    float4 a = o4[c];
    uint2 pk;
    pk.x = pack2_bf16(a.x * inv, a.y * inv);
    pk.y = pack2_bf16(a.z * inv, a.w * inv);
    *reinterpret_cast<uint2*>(dst + c * 4) = pk;
  }
}

// ---------------- out-proj GEMM: out = A @ out_w^T + out_b (f32 out) ----------------
__global__ __launch_bounds__(256) void gemm_out(const u16* __restrict__ ab,
                                                const u16* __restrict__ owb,
                                                const float* __restrict__ out_b,
                                                float* __restrict__ out) {
  __shared__ __align__(16) u16 Al[128 * 64];
  __shared__ __align__(16) u16 Bl[128 * 64];
  const int lane = threadIdx.x & 63, w = threadIdx.x >> 6;
  const int quad = lane >> 4, colr = lane & 15;
  const int mw = (w >> 1) * 64, nw = (w & 1) * 64;
  const int m0 = blockIdx.x * 128, n0 = blockIdx.y * 128;
  f32x4 acc[4][4];
  #pragma unroll
  for (int mt = 0; mt < 4; ++mt)
    #pragma unroll
    for (int nt = 0; nt < 4; ++nt) acc[mt][nt] = (f32x4){0.f, 0.f, 0.f, 0.f};
  gemm_core(ab, owb, CC, Al, Bl, m0, n0, acc);
  float bias[4];
  #pragma unroll
  for (int nt = 0; nt < 4; ++nt) bias[nt] = out_b[n0 + nw + nt * 16 + colr];
  #pragma unroll
  for (int mt = 0; mt < 4; ++mt)
    #pragma unroll
    for (int e = 0; e < 4; ++e) {
      int row = m0 + mw + mt * 16 + quad * 4 + e;
      #pragma unroll
      for (int nt = 0; nt < 4; ++nt)
        out[(size_t)row * CC + n0 + nw + nt * 16 + colr] = acc[mt][nt][e] + bias[nt];
    }
}

extern "C" void kernel_launch(void* const* d_in, const int* in_sizes, int n_in,
                              void* d_out, int out_size, void* d_ws, size_t ws_size,
                              hipStream_t stream) {
  const float* x     = (const float*)d_in[0];
  const float* in_w  = (const float*)d_in[1];
  const float* in_b  = (const float*)d_in[2];
  const float* out_w = (const float*)d_in[3];
  const float* out_b = (const float*)d_in[4];
  float* out = (float*)d_out;

  char* ws = (char*)d_ws;
  u16* xb   = (u16*)(ws + 0);          //  8 MB (dead after gemm_qkv)
  u16* ab   = (u16*)(ws + 0);          //  8 MB attn out (reuses xb)
  u16* wb   = (u16*)(ws + 8388608);    //  6 MB (permuted)
  u16* owb  = (u16*)(ws + 14680064);   //  2 MB
  float* po = (float*)(ws + 16777216);           // 16 MB partial o [slot][64][64]
  float* pl = (float*)(ws + 16777216 + 16777216); // 256 KB partial l
  u16* qkv  = (u16*)(ws + 41943040);   // 24 MB [s][bh][t][d]

  hipMemsetAsync(po, 0, 16777216 + 262144, stream);
  cast_all<<<dim3((N4_X + N4_W + N4_OW) / 256), 256, 0, stream>>>(x, in_w, out_w, xb, wb, owb);

  gemm_qkv<<<dim3(MM / 128, N3 / 128), 256, 0, stream>>>(xb, wb, in_b, qkv);
  attn_mfma<<<dim3(2048), 128, 0, stream>>>(qkv, po, pl);
  attn_finalize<<<dim3(1024), 256, 0, stream>>>(po, pl, ab);
  gemm_out<<<dim3(MM / 128, CC / 128), 256, 0, stream>>>(ab, owb, out_b, out);
}

// Round 10
// 204.975 us; speedup vs baseline: 1.2023x; 1.2023x over previous
//
#include <hip/hip_runtime.h>

// MultiHeadSelfAttention: B=2 T=2048 C=1024 H=16 D=64, causal, f32 in/out.
// R9: attn = R7 split-2 partition + NON-atomic partials (R8 lesson: 12.6M
// device atomics => memory-bound, 46/93 MB FETCH/WRITE) + R8 keepers: S^T
// orientation with in-lane bf16 P packing, lean Pl, direct-qkv GEMM (no
// repack), K pre-scaled by D^-0.5*log2e. Dbuf Vt (one barrier/j-tile).
// einops factoring: col c of (3C) = d*48 + s*16 + h, with s: 0=Q, 1=V, 2=K.

#define BB 2
#define TT 2048
#define CC 1024
#define HH 16
#define DD 64
#define MM (BB*TT)   // 4096
#define N3 (3*CC)    // 3072
#define BH (BB*HH)   // 32
#define KSCALE 0.18033688011112042f  // 1/8 * log2(e)

typedef unsigned short u16;
typedef unsigned int   u32;
typedef __bf16 bf16x8 __attribute__((ext_vector_type(8)));
typedef float  f32x4  __attribute__((ext_vector_type(4)));

__device__ __forceinline__ u16 f32_to_bf16(float f) {
  u32 u = __float_as_uint(f);
  return (u16)((u + 0x7fffu + ((u >> 16) & 1u)) >> 16);  // RNE
}
__device__ __forceinline__ u32 pack2_bf16(float a, float b) {
  u32 ua = __float_as_uint(a) + 0x8000u;
  u32 ub = __float_as_uint(b) + 0x8000u;
  return __builtin_amdgcn_perm(ub, ua, 0x07060302);  // bf16(a) | bf16(b)<<16
}

// ---------------- fused cast f32 -> bf16; in_w rows PERMUTED ----------------
// wb row r' = s*1024 + h*64 + d  <-  in_w row d*48 + s*16 + h
#define N4_X  (MM * CC / 4)          // 1048576
#define N4_W  (N3 * CC / 4)          //  786432
#define N4_OW (CC * CC / 4)          //  262144
__global__ __launch_bounds__(256) void cast_all(const float* __restrict__ x,
                                                const float* __restrict__ in_w,
                                                const float* __restrict__ out_w,
                                                u16* __restrict__ xb,
                                                u16* __restrict__ wb,
                                                u16* __restrict__ owb) {
  int i = blockIdx.x * 256 + threadIdx.x;
  const float* src; u16* dst; int j; int sj;
  if (i < N4_X)             { src = x;     dst = xb;  j = i;               sj = j; }
  else if (i < N4_X + N4_W) { src = in_w;  dst = wb;  j = i - N4_X;
                              int rp = j >> 8, c = j & 255;
                              int s = rp >> 10, h = (rp >> 6) & 15, d = rp & 63;
                              sj = (d * 48 + s * 16 + h) * 256 + c; }
  else                      { src = out_w; dst = owb; j = i - N4_X - N4_W; sj = j; }
  float4 f = reinterpret_cast<const float4*>(src)[sj];
  uint2 pk;
  pk.x = (u32)f32_to_bf16(f.x) | ((u32)f32_to_bf16(f.y) << 16);
  pk.y = (u32)f32_to_bf16(f.z) | ((u32)f32_to_bf16(f.w) << 16);
  reinterpret_cast<uint2*>(dst)[j] = pk;
}

// ---------------- tiled GEMM core: 128x128 tile, BK=64, 4 waves (verified R2) ----------------
__device__ __forceinline__ void gemm_core(const u16* __restrict__ Ag,
                                          const u16* __restrict__ Bg,
                                          int K, u16* Al, u16* Bl,
                                          int m0, int n0, f32x4 acc[4][4]) {
  const int tid = threadIdx.x, lane = tid & 63, w = tid >> 6;
  const int quad = lane >> 4, colr = lane & 15;
  const int mw = (w >> 1) * 64, nw = (w & 1) * 64;
  const int srow = lane >> 3, scol = lane & 7;
  const uint4* Al4 = reinterpret_cast<const uint4*>(Al);
  const uint4* Bl4 = reinterpret_cast<const uint4*>(Bl);
  for (int kt = 0; kt < K / 64; ++kt) {
    __syncthreads();
    #pragma unroll
    for (int ii = 0; ii < 4; ++ii) {
      int inst = w * 4 + ii;
      int row = inst * 8 + srow;
      int cs = scol ^ (row & 7);
      const u16* ga = Ag + (size_t)(m0 + row) * K + kt * 64 + cs * 8;
      const u16* gb = Bg + (size_t)(n0 + row) * K + kt * 64 + cs * 8;
      __builtin_amdgcn_global_load_lds(
          (const __attribute__((address_space(1))) void*)ga,
          (__attribute__((address_space(3))) void*)(Al + inst * 512), 16, 0, 0);
      __builtin_amdgcn_global_load_lds(
          (const __attribute__((address_space(1))) void*)gb,
          (__attribute__((address_space(3))) void*)(Bl + inst * 512), 16, 0, 0);
    }
    __syncthreads();
    #pragma unroll
    for (int ks = 0; ks < 2; ++ks) {
      bf16x8 af[4], bfr[4];
      #pragma unroll
      for (int t = 0; t < 4; ++t) {
        int mrow = mw + t * 16 + colr;
        af[t]  = __builtin_bit_cast(bf16x8, Al4[mrow * 8 + ((ks * 4 + quad) ^ (mrow & 7))]);
        int nrow = nw + t * 16 + colr;
        bfr[t] = __builtin_bit_cast(bf16x8, Bl4[nrow * 8 + ((ks * 4 + quad) ^ (nrow & 7))]);
      }
      #pragma unroll
      for (int mt = 0; mt < 4; ++mt)
        #pragma unroll
        for (int nt = 0; nt < 4; ++nt)
          acc[mt][nt] = __builtin_amdgcn_mfma_f32_16x16x32_bf16(af[mt], bfr[nt], acc[mt][nt], 0, 0, 0);
    }
  }
}

// ---------------- QKV GEMM: writes qkv [s][bh][t][d] directly (R8, verified) ----------------
__global__ __launch_bounds__(256) void gemm_qkv(const u16* __restrict__ xb,
                                                const u16* __restrict__ wb,
                                                const float* __restrict__ in_b,
                                                u16* __restrict__ qkv) {
  __shared__ __align__(16) u16 Al[128 * 64];
  __shared__ __align__(16) u16 Bl[128 * 64];
  const int lane = threadIdx.x & 63, w = threadIdx.x >> 6;
  const int quad = lane >> 4, colr = lane & 15;
  const int mw = (w >> 1) * 64, nw = (w & 1) * 64;
  const int m0 = blockIdx.x * 128, n0 = blockIdx.y * 128;
  f32x4 acc[4][4];
  #pragma unroll
  for (int mt = 0; mt < 4; ++mt)
    #pragma unroll
    for (int nt = 0; nt < 4; ++nt) acc[mt][nt] = (f32x4){0.f, 0.f, 0.f, 0.f};
  gemm_core(xb, wb, CC, Al, Bl, m0, n0, acc);
  const int b_ = m0 >> 11;
  #pragma unroll
  for (int nt = 0; nt < 4; ++nt) {
    int np = n0 + nw + nt * 16 + colr;        // permuted col = s*1024+h*64+d
    int s = np >> 10, h = (np >> 6) & 15, d = np & 63;
    float bias = in_b[d * 48 + s * 16 + h];
    float sc = (s == 2) ? KSCALE : 1.0f;
    u16* base = qkv + ((size_t)(s * BH + b_ * HH + h) * TT) * DD + d;
    #pragma unroll
    for (int mt = 0; mt < 4; ++mt)
      #pragma unroll
      for (int e = 0; e < 4; ++e) {
        int t = (m0 + mw + mt * 16 + quad * 4 + e) & (TT - 1);
        base[(size_t)t * DD] = f32_to_bf16((acc[mt][nt][e] + bias) * sc);
      }
  }
}

// ---------------- MFMA flash attention v3: S^T + split-2 + private partials ----------------
// 1024 blocks x 128 thr (2 waves x 32-row strips). f: xcd=f&7, hf=(f>>3)&1,
// pr=(f>>4)&15, bh=xcd*4+(f>>8) (4 bh per XCD).
// hf=0: [qt=pr, j 0..pr, FINAL] + [qt=31-pr, j 0..15-pr -> slot s0]
// hf=1: [qt=31-pr, j 16-pr..31-pr -> slot s1]      (17 vs 16 j-tiles)
// Partials written ONCE to private slots (no atomics). S^T: sacc[u][t4] holds
// S^T[j=t4*16+quad*4+rg][q=u*16+colr] -> exp2+pack in-lane; Pl row q = P[q][j]
// bf16 -> A-frag b128 reads. Dbuf Vt: one barrier per j-tile.
__global__ __launch_bounds__(128, 2) void attn_mfma(const u16* __restrict__ qkv,
                                                    u16* __restrict__ aout,
                                                    float* __restrict__ po,
                                                    float* __restrict__ pl) {
  __shared__ __align__(16) u32 Vt[2][64 * 36];   // V^T bf16-pairs, dbuf
  __shared__ __align__(16) u32 Pl[2 * 32 * 36];  // per-wave P bf16 rows (q x j)
  const int tid  = threadIdx.x;
  const int lane = tid & 63, w = tid >> 6;       // w in 0..1
  const int quad = lane >> 4, colr = lane & 15;
  const int f = blockIdx.x;
  const int hf = (f >> 3) & 1;
  const int pr = (f >> 4) & 15;
  const int bh = (f & 7) * 4 + (f >> 8);
  const int b_ = bh >> 4, h = bh & 15;
  const int slot = (((bh << 4) + pr) << 1) | hf;

  const uint4* Qg4 = reinterpret_cast<const uint4*>(qkv + (size_t)bh * TT * DD);
  const uint4* Vg4 = reinterpret_cast<const uint4*>(qkv + ((size_t)BH + bh) * TT * DD);
  const uint4* Kg4 = reinterpret_cast<const uint4*>(qkv + ((size_t)2 * BH + bh) * TT * DD);
  const uint4* Pl4 = reinterpret_cast<const uint4*>(Pl);

  const int s_jp = tid & 31, s_half = tid >> 5;  // V staging map
  const int wb32 = w * (32 * 36);                // Pl word base per wave

  const int nseg = 2 - hf;
  for (int sg = 0; sg < nseg; ++sg) {
    const bool final_out = (hf == 0) && (sg == 0);
    const int qt  = final_out ? pr : (31 - pr);
    const int jlo = (hf == 1) ? (16 - pr) : 0;
    const int jhi = (hf == 1) ? (31 - pr) : (sg == 0 ? pr : 15 - pr);
    const int i0 = qt * 64;

    bf16x8 qa[2][2];
    #pragma unroll
    for (int u = 0; u < 2; ++u)
      #pragma unroll
      for (int ks = 0; ks < 2; ++ks)
        qa[u][ks] = __builtin_bit_cast(bf16x8,
            Qg4[(size_t)(i0 + w * 32 + u * 16 + colr) * 8 + ks * 4 + quad]);

    f32x4 oacc[2][4];
    #pragma unroll
    for (int u = 0; u < 2; ++u)
      #pragma unroll
      for (int dt = 0; dt < 4; ++dt) oacc[u][dt] = (f32x4){0.f, 0.f, 0.f, 0.f};
    float lp[2] = {0.f, 0.f};

    uint4 va[2], vb[2];
    #pragma unroll
    for (int io = 0; io < 2; ++io) {
      va[io] = Vg4[(size_t)(jlo * 64 + 2 * s_jp) * 8 + s_half + io * 4];
      vb[io] = Vg4[(size_t)(jlo * 64 + 2 * s_jp + 1) * 8 + s_half + io * 4];
    }

    for (int jt = jlo; jt <= jhi; ++jt) {
      const int j0 = jt * 64;
      u32* vtw = Vt[jt & 1];
      const uint4* vt4 = reinterpret_cast<const uint4*>(Vt[jt & 1]);

      // stage V^T tile jt into buf[jt&1] (prefetched regs)
      #pragma unroll
      for (int io = 0; io < 2; ++io) {
        const int oc = s_half + io * 4;
        u32 aw[4] = {va[io].x, va[io].y, va[io].z, va[io].w};
        u32 bw[4] = {vb[io].x, vb[io].y, vb[io].z, vb[io].w};
        #pragma unroll
        for (int m = 0; m < 4; ++m) {
          vtw[(oc * 8 + 2 * m)     * 36 + s_jp] = __builtin_amdgcn_perm(bw[m], aw[m], 0x05040100);
          vtw[(oc * 8 + 2 * m + 1) * 36 + s_jp] = __builtin_amdgcn_perm(bw[m], aw[m], 0x07060302);
        }
      }
      if (jt < jhi) {
        int nj = j0 + 64;
        #pragma unroll
        for (int io = 0; io < 2; ++io) {
          va[io] = Vg4[(size_t)(nj + 2 * s_jp) * 8 + s_half + io * 4];
          vb[io] = Vg4[(size_t)(nj + 2 * s_jp + 1) * 8 + s_half + io * 4];
        }
      }
      __syncthreads();  // buf[jt&1] ready; prev tile's readers used other buf

      // ---- S^T = K·Q^T (A=K so m=j; B=Q so n=q), ks-split K loads ----
      f32x4 sacc[2][4];
      #pragma unroll
      for (int u = 0; u < 2; ++u)
        #pragma unroll
        for (int t4 = 0; t4 < 4; ++t4) sacc[u][t4] = (f32x4){0.f, 0.f, 0.f, 0.f};
      #pragma unroll
      for (int ks = 0; ks < 2; ++ks) {
        uint4 kk[4];
        #pragma unroll
        for (int t4 = 0; t4 < 4; ++t4)
          kk[t4] = Kg4[(size_t)(j0 + t4 * 16 + colr) * 8 + ks * 4 + quad];
        #pragma unroll
        for (int t4 = 0; t4 < 4; ++t4) {
          bf16x8 kb = __builtin_bit_cast(bf16x8, kk[t4]);
          #pragma unroll
          for (int u = 0; u < 2; ++u)
            sacc[u][t4] = __builtin_amdgcn_mfma_f32_16x16x32_bf16(kb, qa[u][ks], sacc[u][t4], 0, 0, 0);
        }
      }

      // ---- exp2 + (diag) mask -> in-lane bf16 pack -> Pl ----
      if (jt == qt) {
        #pragma unroll
        for (int u = 0; u < 2; ++u) {
          const int qv = w * 32 + u * 16 + colr;
          #pragma unroll
          for (int t4 = 0; t4 < 4; ++t4) {
            float p0 = __builtin_amdgcn_exp2f(sacc[u][t4][0]);
            float p1 = __builtin_amdgcn_exp2f(sacc[u][t4][1]);
            float p2 = __builtin_amdgcn_exp2f(sacc[u][t4][2]);
            float p3 = __builtin_amdgcn_exp2f(sacc[u][t4][3]);
            int jb = t4 * 16 + quad * 4;
            if (jb + 0 > qv) p0 = 0.f;
            if (jb + 1 > qv) p1 = 0.f;
            if (jb + 2 > qv) p2 = 0.f;
            if (jb + 3 > qv) p3 = 0.f;
            lp[u] += (p0 + p1) + (p2 + p3);
            uint2 pw; pw.x = pack2_bf16(p0, p1); pw.y = pack2_bf16(p2, p3);
            *reinterpret_cast<uint2*>(Pl + wb32 + (u * 16 + colr) * 36 + t4 * 8 + quad * 2) = pw;
          }
        }
      } else {
        #pragma unroll
        for (int u = 0; u < 2; ++u)
          #pragma unroll
          for (int t4 = 0; t4 < 4; ++t4) {
            float p0 = __builtin_amdgcn_exp2f(sacc[u][t4][0]);
            float p1 = __builtin_amdgcn_exp2f(sacc[u][t4][1]);
            float p2 = __builtin_amdgcn_exp2f(sacc[u][t4][2]);
            float p3 = __builtin_amdgcn_exp2f(sacc[u][t4][3]);
            lp[u] += (p0 + p1) + (p2 + p3);
            uint2 pw; pw.x = pack2_bf16(p0, p1); pw.y = pack2_bf16(p2, p3);
            *reinterpret_cast<uint2*>(Pl + wb32 + (u * 16 + colr) * 36 + t4 * 8 + quad * 2) = pw;
          }
      }

      // ---- PV: A = P rows (Pl b128), B = V^T frags ----
      #pragma unroll
      for (int u = 0; u < 2; ++u) {
        bf16x8 pa[2];
        #pragma unroll
        for (int ks = 0; ks < 2; ++ks)
          pa[ks] = __builtin_bit_cast(bf16x8,
              Pl4[(wb32 + (u * 16 + colr) * 36 + ks * 16 + quad * 4) >> 2]);
        #pragma unroll
        for (int dt = 0; dt < 4; ++dt)
          #pragma unroll
          for (int ks = 0; ks < 2; ++ks) {
            bf16x8 vfr = __builtin_bit_cast(bf16x8, vt4[(dt * 16 + colr) * 9 + ks * 4 + quad]);
            oacc[u][dt] = __builtin_amdgcn_mfma_f32_16x16x32_bf16(pa[ks], vfr, oacc[u][dt], 0, 0, 0);
          }
      }
    }

    // ---- epilogue: O[q=i0+w*32+u*16+quad*4+rg][d=dt*16+colr] ----
    #pragma unroll
    for (int u = 0; u < 2; ++u) {
      float ls = lp[u];
      ls += __shfl_xor(ls, 16);
      ls += __shfl_xor(ls, 32);   // lane colr holds l[q=u*16+colr], replicated
      if (final_out) {
        float linv[4];
        #pragma unroll
        for (int rg = 0; rg < 4; ++rg)
          linv[rg] = 1.0f / __shfl(ls, quad * 4 + rg);
        #pragma unroll
        for (int dt = 0; dt < 4; ++dt)
          #pragma unroll
          for (int rg = 0; rg < 4; ++rg) {
            int ig = i0 + w * 32 + u * 16 + quad * 4 + rg;
            size_t off = ((size_t)(b_ * TT + ig)) * CC + h * DD + dt * 16 + colr;
            aout[off] = (u16)((__float_as_uint(oacc[u][dt][rg] * linv[rg]) + 0x8000u) >> 16);
          }
      } else {
        float* ob = po + (size_t)slot * 4096;
        #pragma unroll
        for (int dt = 0; dt < 4; ++dt)
          #pragma unroll
          for (int rg = 0; rg < 4; ++rg)
            ob[(w * 32 + u * 16 + quad * 4 + rg) * 64 + dt * 16 + colr] = oacc[u][dt][rg];
        if (quad == 0) pl[slot * 64 + w * 32 + u * 16 + colr] = ls;
      }
    }
    __syncthreads();  // all Vt reads done before next segment restages
  }
}

// ---------------- finalize split Q-tiles (qt 16..31): o = (o0+o1)/(l0+l1) ----------------
__global__ __launch_bounds__(256) void attn_finalize(const float* __restrict__ po,
                                                     const float* __restrict__ pl,
                                                     u16* __restrict__ ab) {
  const int blk = blockIdx.x;       // bh*16 + pr
  const int bh = blk >> 4, pr = blk & 15;
  const int qt = 31 - pr;
  const int b_ = bh >> 4, h = bh & 15;
  const int t = threadIdx.x;
  const int r = t >> 2, dq = t & 3;
  const size_t s0 = (size_t)blk * 2, s1 = s0 + 1;
  const float4* o0 = reinterpret_cast<const float4*>(po + s0 * 4096 + r * 64 + dq * 16);
  const float4* o1 = reinterpret_cast<const float4*>(po + s1 * 4096 + r * 64 + dq * 16);
  float inv = 1.0f / (pl[s0 * 64 + r] + pl[s1 * 64 + r]);
  u16* dst = ab + ((size_t)(b_ * TT + qt * 64 + r)) * CC + h * DD + dq * 16;
  #pragma unroll
  for (int c = 0; c < 4; ++c) {
    float4 a = o0[c], b = o1[c];
    uint2 pk;
    pk.x = pack2_bf16((a.x + b.x) * inv, (a.y + b.y) * inv);
    pk.y = pack2_bf16((a.z + b.z) * inv, (a.w + b.w) * inv);
    *reinterpret_cast<uint2*>(dst + c * 4) = pk;
  }
}

// ---------------- out-proj GEMM: out = A @ out_w^T + out_b (f32 out) ----------------
__global__ __launch_bounds__(256) void gemm_out(const u16* __restrict__ ab,
                                                const u16* __restrict__ owb,
                                                const float* __restrict__ out_b,
                                                float* __restrict__ out) {
  __shared__ __align__(16) u16 Al[128 * 64];
  __shared__ __align__(16) u16 Bl[128 * 64];
  const int lane = threadIdx.x & 63, w = threadIdx.x >> 6;
  const int quad = lane >> 4, colr = lane & 15;
  const int mw = (w >> 1) * 64, nw = (w & 1) * 64;
  const int m0 = blockIdx.x * 128, n0 = blockIdx.y * 128;
  f32x4 acc[4][4];
  #pragma unroll
  for (int mt = 0; mt < 4; ++mt)
    #pragma unroll
    for (int nt = 0; nt < 4; ++nt) acc[mt][nt] = (f32x4){0.f, 0.f, 0.f, 0.f};
  gemm_core(ab, owb, CC, Al, Bl, m0, n0, acc);
  float bias[4];
  #pragma unroll
  for (int nt = 0; nt < 4; ++nt) bias[nt] = out_b[n0 + nw + nt * 16 + colr];
  #pragma unroll
  for (int mt = 0; mt < 4; ++mt)
    #pragma unroll
    for (int e = 0; e < 4; ++e) {
      int row = m0 + mw + mt * 16 + quad * 4 + e;
      #pragma unroll
      for (int nt = 0; nt < 4; ++nt)
        out[(size_t)row * CC + n0 + nw + nt * 16 + colr] = acc[mt][nt][e] + bias[nt];
    }
}

extern "C" void kernel_launch(void* const* d_in, const int* in_sizes, int n_in,
                              void* d_out, int out_size, void* d_ws, size_t ws_size,
                              hipStream_t stream) {
  const float* x     = (const float*)d_in[0];
  const float* in_w  = (const float*)d_in[1];
  const float* in_b  = (const float*)d_in[2];
  const float* out_w = (const float*)d_in[3];
  const float* out_b = (const float*)d_in[4];
  float* out = (float*)d_out;

  char* ws = (char*)d_ws;
  u16* xb   = (u16*)(ws + 0);          //  8 MB (dead after gemm_qkv)
  u16* ab   = (u16*)(ws + 0);          //  8 MB attn out (reuses xb)
  u16* wb   = (u16*)(ws + 8388608);    //  6 MB (permuted)
  u16* owb  = (u16*)(ws + 14680064);   //  2 MB
  float* po = (float*)(ws + 16777216);            // 16.8 MB partial o [slot][64][64]
  float* pl = (float*)(ws + 16777216 + 16777216); // 256 KB partial l
  u16* qkv  = (u16*)(ws + 41943040);   // 24 MB [s][bh][t][d]

  cast_all<<<dim3((N4_X + N4_W + N4_OW) / 256), 256, 0, stream>>>(x, in_w, out_w, xb, wb, owb);

  gemm_qkv<<<dim3(MM / 128, N3 / 128), 256, 0, stream>>>(xb, wb, in_b, qkv);
  attn_mfma<<<dim3(1024), 128, 0, stream>>>(qkv, ab, po, pl);
  attn_finalize<<<dim3(512), 256, 0, stream>>>(po, pl, ab);
  gemm_out<<<dim3(MM / 128, CC / 128), 256, 0, stream>>>(ab, owb, out_b, out);
}